// Round 2
// baseline (72.411 us; speedup 1.0000x reference)
//
#include <hip/hip_runtime.h>

#define MCW_EPS 1e-32f

// ---------------------------------------------------------------------------
// Main pass: stream output+labels once (latency-optimized round 2).
//   Per column c: sum_s_pos[c], sum_s_neg[c], n_pos[c]   (float atomics)
//   Global:       sum(l*log(s+eps)), sum((1-l)*log(1-s+eps))  (double atomics)
// Layout: row-major [B, 256]. Block = 256 threads; thread t owns 4 columns
// (c0 = 4*(t&63)) of row lane_rg within each 4-row group -> float4 loads,
// 16B/lane fully coalesced.
// R2 changes vs R1: UNROLL=2 row-groups (4 independent float4 loads in
// flight), branchless inner body (labels are exactly 0.0/1.0), rcp approx,
// __launch_bounds__(256,8) + grid 2048 for full 32-wave/CU occupancy.
// ---------------------------------------------------------------------------
__global__ __launch_bounds__(256, 8) void mcwauc_main(
    const float* __restrict__ x_, const float* __restrict__ l_,
    int rowGroups,
    float* __restrict__ g_sp, float* __restrict__ g_sn, float* __restrict__ g_np,
    double* __restrict__ g_logs)
{
    const int t       = threadIdx.x;
    const int lane_rg = t >> 6;          // which of 4 rows in the row-group
    const int c0      = (t & 63) << 2;   // base column (4 consecutive cols)

    float sp[4] = {0.f, 0.f, 0.f, 0.f};
    float sn[4] = {0.f, 0.f, 0.f, 0.f};
    float np[4] = {0.f, 0.f, 0.f, 0.f};
    float lp = 0.f, ln = 0.f;

    constexpr int UNROLL = 2;
    const size_t laneOff = (size_t)lane_rg * 256 + c0;
    const int    stride  = gridDim.x * UNROLL;

    for (int rg0 = blockIdx.x * UNROLL; rg0 < rowGroups; rg0 += stride) {
        // ---- issue all loads up front (independent -> overlapped) ----
        float4 xv[UNROLL], lv[UNROLL];
        #pragma unroll
        for (int u = 0; u < UNROLL; ++u) {
            const size_t idx = (size_t)(rg0 + u) * (256 * 4) + laneOff;
            xv[u] = *reinterpret_cast<const float4*>(x_ + idx);
            lv[u] = *reinterpret_cast<const float4*>(l_ + idx);
        }
        // ---- branchless compute ----
        #pragma unroll
        for (int u = 0; u < UNROLL; ++u) {
            #pragma unroll
            for (int k = 0; k < 4; ++k) {
                const float xw = (&xv[u].x)[k];
                const float lw = (&lv[u].x)[k];      // exactly 0.0f or 1.0f
                const float e  = __expf(-xw);
                const float s  = __builtin_amdgcn_rcpf(1.f + e);  // sigmoid
                const float s1 = e * s;              // 1 - sigmoid, no cancel
                const float sel = (lw != 0.f) ? s : s1;
                const float lg  = __logf(sel + MCW_EPS);
                sp[k] = fmaf(lw, s, sp[k]);
                sn[k] += s - lw * s;
                np[k] += lw;
                lp    = fmaf(lw, lg, lp);
                ln   += lg - lw * lg;
            }
        }
    }

    // ---- block reduce per-column partials (4 row-lanes -> 1 per column) ----
    __shared__ float rp[4][256];
    __shared__ float rn[4][256];
    __shared__ float rc[4][256];
    #pragma unroll
    for (int k = 0; k < 4; ++k) {
        rp[lane_rg][c0 + k] = sp[k];
        rn[lane_rg][c0 + k] = sn[k];
        rc[lane_rg][c0 + k] = np[k];
    }

    // ---- wave-reduce the global log sums while LDS settles ----
    #pragma unroll
    for (int o = 32; o > 0; o >>= 1) {
        lp += __shfl_down(lp, o);
        ln += __shfl_down(ln, o);
    }
    __shared__ float wl[2][4];
    if ((t & 63) == 0) { wl[0][t >> 6] = lp; wl[1][t >> 6] = ln; }

    __syncthreads();

    {
        const int c = t;  // 256 threads == 256 columns
        const float a = rp[0][c] + rp[1][c] + rp[2][c] + rp[3][c];
        const float b = rn[0][c] + rn[1][c] + rn[2][c] + rn[3][c];
        const float d = rc[0][c] + rc[1][c] + rc[2][c] + rc[3][c];
        atomicAdd(&g_sp[c], a);
        atomicAdd(&g_sn[c], b);
        atomicAdd(&g_np[c], d);
    }
    if (t == 0) {
        atomicAdd(&g_logs[0], (double)(wl[0][0] + wl[0][1] + wl[0][2] + wl[0][3]));
        atomicAdd(&g_logs[1], (double)(wl[1][0] + wl[1][1] + wl[1][2] + wl[1][3]));
    }
}

// ---------------------------------------------------------------------------
// Finalize: 1 block x 256 threads (one per column).
// ---------------------------------------------------------------------------
__global__ __launch_bounds__(256) void mcwauc_fin(
    const float* __restrict__ g_sp, const float* __restrict__ g_sn,
    const float* __restrict__ g_np, const double* __restrict__ g_logs,
    float* __restrict__ out, int B)
{
    const int c = threadIdx.x;
    const float np = g_np[c];
    const float nn = (float)B - np;
    const float mp = g_sp[c] / fmaxf(np, 1.f);
    const float mn = g_sn[c] / fmaxf(nn, 1.f);

    float pen;
    if (np > 0.f && nn > 0.f)      pen = 1.f - mp + mn;
    else if (np == 0.f)            pen = 1.f + mn;
    else                           pen = 1.f - mp;

    // reduce pen-sum and num_P across the 256 threads
    float psum = pen, csum = np;
    #pragma unroll
    for (int o = 32; o > 0; o >>= 1) {
        psum += __shfl_down(psum, o);
        csum += __shfl_down(csum, o);
    }
    __shared__ float sps[4], scs[4];
    if ((c & 63) == 0) { sps[c >> 6] = psum; scs[c >> 6] = csum; }
    __syncthreads();

    if (c == 255) out[1] = 0.1f * pen;   // penalty term of the LAST category
    if (c == 0) {
        const double pensum = (double)sps[0] + sps[1] + sps[2] + sps[3];
        const double numP   = (double)scs[0] + scs[1] + scs[2] + scs[3];
        const double total  = (double)B * 256.0;
        const double aP = numP / total;
        const double aN = 1.0 - aP;
        const double cel = -aN * (g_logs[0] / total) - aP * (g_logs[1] / total);
        const double cls = cel + 0.1 * (pensum / 256.0);
        out[0] = (float)cls;
    }
}

extern "C" void kernel_launch(void* const* d_in, const int* in_sizes, int n_in,
                              void* d_out, int out_size, void* d_ws, size_t ws_size,
                              hipStream_t stream) {
    const float* x = (const float*)d_in[0];
    const float* l = (const float*)d_in[1];
    const int n = in_sizes[0];
    const int B = n / 256;

    float*  g_sp   = (float*)d_ws;
    float*  g_sn   = g_sp + 256;
    float*  g_np   = g_sn + 256;
    double* g_logs = (double*)((char*)d_ws + 3 * 256 * sizeof(float)); // 3072 % 8 == 0

    // zero the accumulators every call (harness poisons ws once; we accumulate)
    hipMemsetAsync(d_ws, 0, 3 * 256 * sizeof(float) + 2 * sizeof(double), stream);

    const int rowGroups = B / 4;           // B = 65536 -> 16384
    int grid = 2048;                       // 8 blocks/CU -> 32 waves/CU
    if (grid * 2 > rowGroups) grid = (rowGroups + 1) / 2;

    mcwauc_main<<<grid, 256, 0, stream>>>(x, l, rowGroups, g_sp, g_sn, g_np, g_logs);
    mcwauc_fin<<<1, 256, 0, stream>>>(g_sp, g_sn, g_np, g_logs, (float*)d_out, B);
}

// Round 3
// 39.029 us; speedup vs baseline: 1.8553x; 1.8553x over previous
//
#include <hip/hip_runtime.h>

#define MCW_EPS 1e-32f

constexpr int NRED = 64;   // stage-2 reduction blocks

// ---------------------------------------------------------------------------
// Stage 1: stream output+labels once. NO ATOMICS (R2's regression was the
// per-column atomicAdd tail: WRITE_SIZE == 4B * #atomics, same-line RMW
// serialization). Each block writes its 768 per-column partials + 2 log
// partials coalesced into d_ws.
// Layout: row-major [B, 256]. Block = 256 threads; thread t owns 4 columns
// (c0 = 4*(t&63)) of row (t>>6) within each 4-row group -> float4 loads,
// 16B/lane fully coalesced.
// ---------------------------------------------------------------------------
__global__ __launch_bounds__(256, 8) void mcwauc_main(
    const float* __restrict__ x_, const float* __restrict__ l_,
    int rowGroups,
    float* __restrict__ P_sp, float* __restrict__ P_sn,
    float* __restrict__ P_np, float* __restrict__ P_lg)
{
    const int t       = threadIdx.x;
    const int lane_rg = t >> 6;          // which of 4 rows in the row-group
    const int c0      = (t & 63) << 2;   // base column (4 consecutive cols)

    float sp[4] = {0.f, 0.f, 0.f, 0.f};
    float sn[4] = {0.f, 0.f, 0.f, 0.f};
    float np[4] = {0.f, 0.f, 0.f, 0.f};
    float lp = 0.f, ln = 0.f;

    constexpr int UNROLL = 2;
    const size_t laneOff = (size_t)lane_rg * 256 + c0;
    const int    stride  = gridDim.x * UNROLL;

    for (int rg0 = blockIdx.x * UNROLL; rg0 < rowGroups; rg0 += stride) {
        float4 xv[UNROLL], lv[UNROLL];
        #pragma unroll
        for (int u = 0; u < UNROLL; ++u) {
            const size_t idx = (size_t)(rg0 + u) * (256 * 4) + laneOff;
            xv[u] = *reinterpret_cast<const float4*>(x_ + idx);
            lv[u] = *reinterpret_cast<const float4*>(l_ + idx);
        }
        #pragma unroll
        for (int u = 0; u < UNROLL; ++u) {
            #pragma unroll
            for (int k = 0; k < 4; ++k) {
                const float xw = (&xv[u].x)[k];
                const float lw = (&lv[u].x)[k];      // exactly 0.0f or 1.0f
                const float e  = __expf(-xw);
                const float s  = __builtin_amdgcn_rcpf(1.f + e);  // sigmoid
                const float s1 = e * s;              // 1 - sigmoid, no cancel
                const float sel = (lw != 0.f) ? s : s1;
                const float lg  = __logf(sel + MCW_EPS);
                sp[k] = fmaf(lw, s, sp[k]);
                sn[k] += s - lw * s;
                np[k] += lw;
                lp    = fmaf(lw, lg, lp);
                ln   += lg - lw * lg;
            }
        }
    }

    // ---- block reduce per-column partials (4 row-lanes -> 1 per column) ----
    __shared__ float rp[4][256];
    __shared__ float rn[4][256];
    __shared__ float rc[4][256];
    #pragma unroll
    for (int k = 0; k < 4; ++k) {
        rp[lane_rg][c0 + k] = sp[k];
        rn[lane_rg][c0 + k] = sn[k];
        rc[lane_rg][c0 + k] = np[k];
    }

    // ---- wave-reduce the global log sums while LDS settles ----
    #pragma unroll
    for (int o = 32; o > 0; o >>= 1) {
        lp += __shfl_down(lp, o);
        ln += __shfl_down(ln, o);
    }
    __shared__ float wl[2][4];
    if ((t & 63) == 0) { wl[0][t >> 6] = lp; wl[1][t >> 6] = ln; }

    __syncthreads();

    // ---- coalesced partial writes (no atomics) ----
    const size_t base = (size_t)blockIdx.x * 256;
    P_sp[base + t] = rp[0][t] + rp[1][t] + rp[2][t] + rp[3][t];
    P_sn[base + t] = rn[0][t] + rn[1][t] + rn[2][t] + rn[3][t];
    P_np[base + t] = rc[0][t] + rc[1][t] + rc[2][t] + rc[3][t];
    if (t == 0) {
        P_lg[2 * blockIdx.x + 0] = wl[0][0] + wl[0][1] + wl[0][2] + wl[0][3];
        P_lg[2 * blockIdx.x + 1] = wl[1][0] + wl[1][1] + wl[1][2] + wl[1][3];
    }
}

// ---------------------------------------------------------------------------
// Stage 2: fold G partials -> NRED partials. Block j reduces chunk=G/NRED
// consecutive partial records; thread c owns column c. Fully coalesced.
// ---------------------------------------------------------------------------
__global__ __launch_bounds__(256) void mcwauc_reduce(
    const float* __restrict__ P_sp, const float* __restrict__ P_sn,
    const float* __restrict__ P_np,
    float* __restrict__ Q_sp, float* __restrict__ Q_sn, float* __restrict__ Q_np,
    int chunk)
{
    const int j = blockIdx.x;
    const int c = threadIdx.x;
    const size_t p0 = (size_t)j * chunk;
    float a = 0.f, b = 0.f, d = 0.f;
    #pragma unroll 4
    for (int p = 0; p < chunk; ++p) {
        const size_t off = (p0 + p) * 256 + c;
        a += P_sp[off];
        b += P_sn[off];
        d += P_np[off];
    }
    const size_t q = (size_t)j * 256 + c;
    Q_sp[q] = a;
    Q_sn[q] = b;
    Q_np[q] = d;
}

// ---------------------------------------------------------------------------
// Stage 3: 1 block x 256 threads (one per column). Fold NRED partials,
// per-column penalty branch, CEL, write the 2 outputs.
// ---------------------------------------------------------------------------
__global__ __launch_bounds__(256) void mcwauc_fin(
    const float* __restrict__ Q_sp, const float* __restrict__ Q_sn,
    const float* __restrict__ Q_np, const float* __restrict__ P_lg,
    float* __restrict__ out, int B, int G)
{
    const int c = threadIdx.x;
    float a = 0.f, b = 0.f, d = 0.f;
    #pragma unroll 8
    for (int j = 0; j < NRED; ++j) {
        const size_t off = (size_t)j * 256 + c;
        a += Q_sp[off];
        b += Q_sn[off];
        d += Q_np[off];
    }
    float lp = 0.f, ln = 0.f;
    for (int p = c; p < G; p += 256) {
        lp += P_lg[2 * p + 0];
        ln += P_lg[2 * p + 1];
    }

    const float np = d;
    const float nn = (float)B - np;
    const float mp = a / fmaxf(np, 1.f);
    const float mn = b / fmaxf(nn, 1.f);

    float pen;
    if (np > 0.f && nn > 0.f)      pen = 1.f - mp + mn;
    else if (np == 0.f)            pen = 1.f + mn;
    else                           pen = 1.f - mp;

    // reduce {pen, np, lp, ln} across the 256 threads
    float psum = pen, csum = np;
    #pragma unroll
    for (int o = 32; o > 0; o >>= 1) {
        psum += __shfl_down(psum, o);
        csum += __shfl_down(csum, o);
        lp   += __shfl_down(lp, o);
        ln   += __shfl_down(ln, o);
    }
    __shared__ float s4[4][4];
    if ((c & 63) == 0) {
        s4[0][c >> 6] = psum;
        s4[1][c >> 6] = csum;
        s4[2][c >> 6] = lp;
        s4[3][c >> 6] = ln;
    }
    __syncthreads();

    if (c == 255) out[1] = 0.1f * pen;   // penalty term of the LAST category
    if (c == 0) {
        const double pensum = (double)s4[0][0] + s4[0][1] + s4[0][2] + s4[0][3];
        const double numP   = (double)s4[1][0] + s4[1][1] + s4[1][2] + s4[1][3];
        const double L0     = (double)s4[2][0] + s4[2][1] + s4[2][2] + s4[2][3];
        const double L1     = (double)s4[3][0] + s4[3][1] + s4[3][2] + s4[3][3];
        const double total  = (double)B * 256.0;
        const double aP = numP / total;
        const double aN = 1.0 - aP;
        const double cel = -aN * (L0 / total) - aP * (L1 / total);
        out[0] = (float)(cel + 0.1 * (pensum / 256.0));
    }
}

extern "C" void kernel_launch(void* const* d_in, const int* in_sizes, int n_in,
                              void* d_out, int out_size, void* d_ws, size_t ws_size,
                              hipStream_t stream) {
    const float* x = (const float*)d_in[0];
    const float* l = (const float*)d_in[1];
    const int n = in_sizes[0];
    const int B = n / 256;
    const int rowGroups = B / 4;           // B = 65536 -> 16384

    // choose G (stage-1 grid / partial count): largest power of two <= 2048
    // whose partial buffers fit in ws. All multiples of NRED=64.
    int G = 2048;
    auto need = [](int g) -> size_t {
        return (size_t)g * 768 * sizeof(float)       // P_sp/sn/np
             + (size_t)g * 2 * sizeof(float)         // P_lg
             + (size_t)NRED * 768 * sizeof(float);   // Q_sp/sn/np
    };
    while (G > NRED && need(G) > ws_size) G >>= 1;

    float* P_sp = (float*)d_ws;
    float* P_sn = P_sp + (size_t)G * 256;
    float* P_np = P_sn + (size_t)G * 256;
    float* P_lg = P_np + (size_t)G * 256;
    float* Q_sp = P_lg + (size_t)G * 2;
    float* Q_sn = Q_sp + (size_t)NRED * 256;
    float* Q_np = Q_sn + (size_t)NRED * 256;

    mcwauc_main<<<G, 256, 0, stream>>>(x, l, rowGroups, P_sp, P_sn, P_np, P_lg);
    mcwauc_reduce<<<NRED, 256, 0, stream>>>(P_sp, P_sn, P_np, Q_sp, Q_sn, Q_np, G / NRED);
    mcwauc_fin<<<1, 256, 0, stream>>>(Q_sp, Q_sn, Q_np, P_lg, (float*)d_out, B, G);
}